// Round 4
// baseline (117.910 us; speedup 1.0000x reference)
//
#include <hip/hip_runtime.h>
#include <math.h>

#define BB 256      // batch
#define CC 1024     // channels
#define CC4 (CC/4)  // row length in float4
#define MARGIN 0.5f
#define NTILE 64    // j-tiles (of 4) per row
#define JPT 4       // j's per tile
#define NP  128     // i-pairs

// ---------------------------------------------------------------------------
// Kernel A: mcsq[i,c] = m_counts[i,c]^2 (float).
// One wave per row i. Partner selection via ballot; float4 loads.
// ---------------------------------------------------------------------------
__global__ __launch_bounds__(64) void mcsq_kernel(
    const float* __restrict__ x, const int* __restrict__ targets,
    const int* __restrict__ subs, const int* __restrict__ m_count_p,
    float* __restrict__ mcsq)
{
    const int i = blockIdx.x;
    const int lane = threadIdx.x;
    const int ti = targets[i], si = subs[i];
    int mc = *m_count_p;
    if (mc > 8) mc = 8;

    unsigned long long masks[4];
    #pragma unroll
    for (int q = 0; q < 4; ++q) {
        const int j = q * 64 + lane;
        masks[q] = __ballot(targets[j] == ti && subs[j] == si);
    }
    int idx[8];
    int cnt = 0;
    for (int q = 0; q < 4 && cnt < mc; ++q) {
        unsigned long long m = masks[q];
        while (m && cnt < mc) {
            const int b = __ffsll(m) - 1;
            idx[cnt++] = q * 64 + b;
            m &= m - 1;
        }
    }
    for (int q = 0; q < 4 && cnt < mc; ++q) {   // stable-argsort padding
        unsigned long long m = ~masks[q];
        while (m && cnt < mc) {
            const int b = __ffsll(m) - 1;
            idx[cnt++] = q * 64 + b;
            m &= m - 1;
        }
    }

    const float4* x4 = (const float4*)x;
    float4 xi[4];
    #pragma unroll
    for (int t = 0; t < 4; ++t) xi[t] = x4[(long)i * CC4 + lane + 64 * t];

    float4 c4[4];
    #pragma unroll
    for (int t = 0; t < 4; ++t) c4[t] = make_float4(0.f, 0.f, 0.f, 0.f);

    for (int k = 0; k < cnt; ++k) {
        float4 ad[4];
        float s = 0.f;
        #pragma unroll
        for (int t = 0; t < 4; ++t) {
            const float4 xj = x4[(long)idx[k] * CC4 + lane + 64 * t];
            ad[t].x = fabsf(xi[t].x - xj.x);
            ad[t].y = fabsf(xi[t].y - xj.y);
            ad[t].z = fabsf(xi[t].z - xj.z);
            ad[t].w = fabsf(xi[t].w - xj.w);
            s += ad[t].x + ad[t].y + ad[t].z + ad[t].w;
        }
        #pragma unroll
        for (int off = 32; off > 0; off >>= 1) s += __shfl_xor(s, off, 64);
        const float thr = s * (MARGIN / CC);   // 0.5 * mean
        #pragma unroll
        for (int t = 0; t < 4; ++t) {
            c4[t].x += (ad[t].x < thr) ? 1.f : 0.f;
            c4[t].y += (ad[t].y < thr) ? 1.f : 0.f;
            c4[t].z += (ad[t].z < thr) ? 1.f : 0.f;
            c4[t].w += (ad[t].w < thr) ? 1.f : 0.f;
        }
    }
    float4* m4 = (float4*)mcsq;
    #pragma unroll
    for (int t = 0; t < 4; ++t) {
        float4 o;
        o.x = c4[t].x * c4[t].x;
        o.y = c4[t].y * c4[t].y;
        o.z = c4[t].z * c4[t].z;
        o.w = c4[t].w * c4[t].w;
        m4[(long)i * CC4 + lane + 64 * t] = o;
    }
}

// ---------------------------------------------------------------------------
// Kernel B: TRIANGULAR pair kernel. All per-pair quantities are symmetric in
// (i,j), and the row reductions are max/min (idempotent), so each unordered
// pair is computed once. Wave = 2 i-rows x 4 j's; only tiles jt >= floor(p/2)
// exist (4160 waves total). Each wave contributes i-side partials
// (pmax/pmin[i][jt]) and j-side transposed partials (pmaxT/pminT[j][p]).
// Wave id -> (p, jt) via inversion of off(h) = 129h - h^2 (h = floor(p/2)).
// ---------------------------------------------------------------------------
__global__ __launch_bounds__(256) void pair_kernel(
    const float* __restrict__ x, const float* __restrict__ mcsq,
    const int* __restrict__ targets,
    float* __restrict__ pmax, float* __restrict__ pmin,
    float* __restrict__ pmaxT, float* __restrict__ pminT)
{
    const int tid  = threadIdx.x;
    const int lane = tid & 63;
    const int gw   = blockIdx.x * 4 + (tid >> 6);  // 0..4159

    // invert off(h) = 129h - h^2  (monotone for h in [0,64])
    int h = (int)((129.0f - sqrtf(16641.0f - 4.0f * (float)gw)) * 0.5f);
    if (h > 63) h = 63;
    if (h < 0) h = 0;
    while (h > 0 && (129 * h - h * h) > gw) --h;
    while ((129 * (h + 1) - (h + 1) * (h + 1)) <= gw) ++h;
    const int r     = gw - (129 * h - h * h);
    const int cnt_h = 64 - h;
    const int p     = 2 * h + r / cnt_h;
    const int jt    = h + r % cnt_h;

    const int i0 = 2 * p, i1 = 2 * p + 1;

    const float4* x4 = (const float4*)x;
    const float4* m4 = (const float4*)mcsq;

    float4 xi0[4], xi1[4], mi0[4], mi1[4];
    #pragma unroll
    for (int t = 0; t < 4; ++t) {
        const int c4 = lane + 64 * t;
        xi0[t] = x4[(long)i0 * CC4 + c4];
        xi1[t] = x4[(long)i1 * CC4 + c4];
        mi0[t] = m4[(long)i0 * CC4 + c4];
        mi1[t] = m4[(long)i1 * CC4 + c4];
    }
    const int t0 = targets[i0], t1 = targets[i1];

    float max0 = 0.f, max1 = 0.f;
    float min0 = INFINITY, min1 = INFINITY;

    for (int jj = 0; jj < JPT; ++jj) {
        const int j = jt * JPT + jj;
        float4 xa[4], ma[4];
        float s0 = 0.f, s1 = 0.f;
        #pragma unroll
        for (int t = 0; t < 4; ++t) {
            const int c4 = lane + 64 * t;
            xa[t] = x4[(long)j * CC4 + c4];
            ma[t] = m4[(long)j * CC4 + c4];
            s0 += fabsf(xi0[t].x - xa[t].x) + fabsf(xi0[t].y - xa[t].y)
                + fabsf(xi0[t].z - xa[t].z) + fabsf(xi0[t].w - xa[t].w);
            s1 += fabsf(xi1[t].x - xa[t].x) + fabsf(xi1[t].y - xa[t].y)
                + fabsf(xi1[t].z - xa[t].z) + fabsf(xi1[t].w - xa[t].w);
        }
        #pragma unroll
        for (int off = 32; off > 0; off >>= 1) {
            s0 += __shfl_xor(s0, off, 64);
            s1 += __shfl_xor(s1, off, 64);
        }
        const float thr0 = s0 * (MARGIN / CC);
        const float thr1 = s1 * (MARGIN / CC);

        float ids0 = 0.f, ids1 = 0.f, md0 = 0.f, md1 = 0.f;
        #pragma unroll
        for (int t = 0; t < 4; ++t) {
            #pragma unroll
            for (int u = 0; u < 4; ++u) {
                const float xav = (&xa[t].x)[u];
                const float mav = (&ma[t].x)[u];
                const float d0 = (&xi0[t].x)[u] - xav;
                const float q0 = d0 * d0;
                ids0 += (fabsf(d0) < thr0) ? q0 : 0.f;
                md0  += q0 * (&mi0[t].x)[u] * mav;
                const float d1 = (&xi1[t].x)[u] - xav;
                const float q1 = d1 * d1;
                ids1 += (fabsf(d1) < thr1) ? q1 : 0.f;
                md1  += q1 * (&mi1[t].x)[u] * mav;
            }
        }
        #pragma unroll
        for (int off = 32; off > 0; off >>= 1) {
            ids0 += __shfl_xor(ids0, off, 64);
            ids1 += __shfl_xor(ids1, off, 64);
            md0  += __shfl_xor(md0,  off, 64);
            md1  += __shfl_xor(md1,  off, 64);
        }
        const float mod0 = sqrtf(fmaxf(md0, 1e-12f));
        const float mod1 = sqrtf(fmaxf(md1, 1e-12f));
        max0 = fmaxf(max0, mod0);
        max1 = fmaxf(max1, mod1);
        float id0 = sqrtf(fmaxf(ids0, 1e-12f));
        float id1 = sqrtf(fmaxf(ids1, 1e-12f));
        const int tj = targets[j];
        if (tj != t0) min0 = fminf(min0, id0); else id0 = INFINITY;
        if (tj != t1) min1 = fminf(min1, id1); else id1 = INFINITY;
        if (lane == 0) {                       // j-side (transposed) partials
            pmaxT[j * NP + p] = fmaxf(mod0, mod1);
            pminT[j * NP + p] = fminf(id0, id1);
        }
    }
    if (lane == 0) {                           // i-side partials
        pmax[i0 * NTILE + jt] = max0;
        pmax[i1 * NTILE + jt] = max1;
        pmin[i0 * NTILE + jt] = min0;
        pmin[i1 * NTILE + jt] = min1;
    }
}

// ---------------------------------------------------------------------------
// Kernel C: final reduce. Row i folds valid i-side slots (jt >= i/4) and
// valid transposed slots (p < 2*(i/4)+2), then block sum -> mean.
// ---------------------------------------------------------------------------
__global__ __launch_bounds__(256) void final_kernel(
    const float* __restrict__ pmax, const float* __restrict__ pmin,
    const float* __restrict__ pmaxT, const float* __restrict__ pminT,
    float* __restrict__ out)
{
    const int i = threadIdx.x;  // row
    const int s = i >> 2;       // first valid jt
    float mx = 0.f, mn = INFINITY;
    for (int t = s; t < NTILE; ++t) {
        mx = fmaxf(mx, pmax[i * NTILE + t]);
        mn = fminf(mn, pmin[i * NTILE + t]);
    }
    const int pv = 2 * s + 2;   // valid p < pv
    for (int p = 0; p < pv; ++p) {
        mx = fmaxf(mx, pmaxT[i * NP + p]);
        mn = fminf(mn, pminT[i * NP + p]);
    }
    float per = fmaxf(mx * 10.f - mn, 0.f);
    __shared__ float red[256];
    red[i] = per;
    __syncthreads();
    for (int off = 128; off > 0; off >>= 1) {
        if (i < off) red[i] += red[i + off];
        __syncthreads();
    }
    if (i == 0) out[0] = red[0] * (1.0f / BB);
}

extern "C" void kernel_launch(void* const* d_in, const int* in_sizes, int n_in,
                              void* d_out, int out_size, void* d_ws, size_t ws_size,
                              hipStream_t stream)
{
    const float* x       = (const float*)d_in[0];
    const int*   targets = (const int*)d_in[1];
    const int*   subs    = (const int*)d_in[2];
    const int*   m_count = (const int*)d_in[3];
    float* out  = (float*)d_out;

    float* mcsq  = (float*)d_ws;                  // BB*CC floats = 1 MB
    float* pmax  = mcsq  + (long)BB * CC;         // BB*NTILE
    float* pmin  = pmax  + BB * NTILE;            // BB*NTILE
    float* pmaxT = pmin  + BB * NTILE;            // BB*NP
    float* pminT = pmaxT + BB * NP;               // BB*NP

    mcsq_kernel <<<BB,   64, 0, stream>>>(x, targets, subs, m_count, mcsq);
    pair_kernel <<<1040, 256, 0, stream>>>(x, mcsq, targets, pmax, pmin, pmaxT, pminT);
    final_kernel<<<1,   256, 0, stream>>>(pmax, pmin, pmaxT, pminT, out);
}

// Round 5
// 95.861 us; speedup vs baseline: 1.2300x; 1.2300x over previous
//
#include <hip/hip_runtime.h>
#include <math.h>

#define BB 256      // batch
#define CC 1024     // channels
#define CC4 (CC/4)  // row length in float4
#define MARGIN 0.5f
#define NTILE 64    // j-tiles (of 4) per row
#define JPT 4       // j's per tile
#define NP  128     // i-pairs

// ---------------------------------------------------------------------------
// Kernel A: mcsq[i,c] = m_counts[i,c]^2 (float).
// One wave per row i. Partner selection via ballot; float4 loads.
// Block 0 also zero-inits the final-reduce accumulator + counter.
// ---------------------------------------------------------------------------
__global__ __launch_bounds__(64) void mcsq_kernel(
    const float* __restrict__ x, const int* __restrict__ targets,
    const int* __restrict__ subs, const int* __restrict__ m_count_p,
    float* __restrict__ mcsq, float* __restrict__ acc,
    unsigned int* __restrict__ cnt_g)
{
    const int i = blockIdx.x;
    const int lane = threadIdx.x;
    if (i == 0 && lane == 0) { *acc = 0.f; *cnt_g = 0u; }
    const int ti = targets[i], si = subs[i];
    int mc = *m_count_p;
    if (mc > 8) mc = 8;

    unsigned long long masks[4];
    #pragma unroll
    for (int q = 0; q < 4; ++q) {
        const int j = q * 64 + lane;
        masks[q] = __ballot(targets[j] == ti && subs[j] == si);
    }
    int idx[8];
    int cnt = 0;
    for (int q = 0; q < 4 && cnt < mc; ++q) {
        unsigned long long m = masks[q];
        while (m && cnt < mc) {
            const int b = __ffsll(m) - 1;
            idx[cnt++] = q * 64 + b;
            m &= m - 1;
        }
    }
    for (int q = 0; q < 4 && cnt < mc; ++q) {   // stable-argsort padding
        unsigned long long m = ~masks[q];
        while (m && cnt < mc) {
            const int b = __ffsll(m) - 1;
            idx[cnt++] = q * 64 + b;
            m &= m - 1;
        }
    }

    const float4* x4 = (const float4*)x;
    float4 xi[4];
    #pragma unroll
    for (int t = 0; t < 4; ++t) xi[t] = x4[(long)i * CC4 + lane + 64 * t];

    float4 c4[4];
    #pragma unroll
    for (int t = 0; t < 4; ++t) c4[t] = make_float4(0.f, 0.f, 0.f, 0.f);

    for (int k = 0; k < cnt; ++k) {
        float4 ad[4];
        float s = 0.f;
        #pragma unroll
        for (int t = 0; t < 4; ++t) {
            const float4 xj = x4[(long)idx[k] * CC4 + lane + 64 * t];
            ad[t].x = fabsf(xi[t].x - xj.x);
            ad[t].y = fabsf(xi[t].y - xj.y);
            ad[t].z = fabsf(xi[t].z - xj.z);
            ad[t].w = fabsf(xi[t].w - xj.w);
            s += ad[t].x + ad[t].y + ad[t].z + ad[t].w;
        }
        #pragma unroll
        for (int off = 32; off > 0; off >>= 1) s += __shfl_xor(s, off, 64);
        const float thr = s * (MARGIN / CC);   // 0.5 * mean
        #pragma unroll
        for (int t = 0; t < 4; ++t) {
            c4[t].x += (ad[t].x < thr) ? 1.f : 0.f;
            c4[t].y += (ad[t].y < thr) ? 1.f : 0.f;
            c4[t].z += (ad[t].z < thr) ? 1.f : 0.f;
            c4[t].w += (ad[t].w < thr) ? 1.f : 0.f;
        }
    }
    float4* m4 = (float4*)mcsq;
    #pragma unroll
    for (int t = 0; t < 4; ++t) {
        float4 o;
        o.x = c4[t].x * c4[t].x;
        o.y = c4[t].y * c4[t].y;
        o.z = c4[t].z * c4[t].z;
        o.w = c4[t].w * c4[t].w;
        m4[(long)i * CC4 + lane + 64 * t] = o;
    }
}

// ---------------------------------------------------------------------------
// Kernel B: TRIANGULAR pair kernel (unchanged from R4). Each unordered pair
// computed once; wave = 2 i-rows x 4 j's; tiles jt >= floor(p/2) only
// (4160 waves). i-side partials pmax/pmin[i][jt]; j-side transposed partials
// pmaxT/pminT[j][p]. Wave id -> (p,jt) via inversion of off(h)=129h-h^2.
// ---------------------------------------------------------------------------
__global__ __launch_bounds__(256) void pair_kernel(
    const float* __restrict__ x, const float* __restrict__ mcsq,
    const int* __restrict__ targets,
    float* __restrict__ pmax, float* __restrict__ pmin,
    float* __restrict__ pmaxT, float* __restrict__ pminT)
{
    const int tid  = threadIdx.x;
    const int lane = tid & 63;
    const int gw   = blockIdx.x * 4 + (tid >> 6);  // 0..4159

    int h = (int)((129.0f - sqrtf(16641.0f - 4.0f * (float)gw)) * 0.5f);
    if (h > 63) h = 63;
    if (h < 0) h = 0;
    while (h > 0 && (129 * h - h * h) > gw) --h;
    while ((129 * (h + 1) - (h + 1) * (h + 1)) <= gw) ++h;
    const int r     = gw - (129 * h - h * h);
    const int cnt_h = 64 - h;
    const int p     = 2 * h + r / cnt_h;
    const int jt    = h + r % cnt_h;

    const int i0 = 2 * p, i1 = 2 * p + 1;

    const float4* x4 = (const float4*)x;
    const float4* m4 = (const float4*)mcsq;

    float4 xi0[4], xi1[4], mi0[4], mi1[4];
    #pragma unroll
    for (int t = 0; t < 4; ++t) {
        const int c4 = lane + 64 * t;
        xi0[t] = x4[(long)i0 * CC4 + c4];
        xi1[t] = x4[(long)i1 * CC4 + c4];
        mi0[t] = m4[(long)i0 * CC4 + c4];
        mi1[t] = m4[(long)i1 * CC4 + c4];
    }
    const int t0 = targets[i0], t1 = targets[i1];

    float max0 = 0.f, max1 = 0.f;
    float min0 = INFINITY, min1 = INFINITY;

    for (int jj = 0; jj < JPT; ++jj) {
        const int j = jt * JPT + jj;
        float4 xa[4], ma[4];
        float s0 = 0.f, s1 = 0.f;
        #pragma unroll
        for (int t = 0; t < 4; ++t) {
            const int c4 = lane + 64 * t;
            xa[t] = x4[(long)j * CC4 + c4];
            ma[t] = m4[(long)j * CC4 + c4];
            s0 += fabsf(xi0[t].x - xa[t].x) + fabsf(xi0[t].y - xa[t].y)
                + fabsf(xi0[t].z - xa[t].z) + fabsf(xi0[t].w - xa[t].w);
            s1 += fabsf(xi1[t].x - xa[t].x) + fabsf(xi1[t].y - xa[t].y)
                + fabsf(xi1[t].z - xa[t].z) + fabsf(xi1[t].w - xa[t].w);
        }
        #pragma unroll
        for (int off = 32; off > 0; off >>= 1) {
            s0 += __shfl_xor(s0, off, 64);
            s1 += __shfl_xor(s1, off, 64);
        }
        const float thr0 = s0 * (MARGIN / CC);
        const float thr1 = s1 * (MARGIN / CC);

        float ids0 = 0.f, ids1 = 0.f, md0 = 0.f, md1 = 0.f;
        #pragma unroll
        for (int t = 0; t < 4; ++t) {
            #pragma unroll
            for (int u = 0; u < 4; ++u) {
                const float xav = (&xa[t].x)[u];
                const float mav = (&ma[t].x)[u];
                const float d0 = (&xi0[t].x)[u] - xav;
                const float q0 = d0 * d0;
                ids0 += (fabsf(d0) < thr0) ? q0 : 0.f;
                md0  += q0 * (&mi0[t].x)[u] * mav;
                const float d1 = (&xi1[t].x)[u] - xav;
                const float q1 = d1 * d1;
                ids1 += (fabsf(d1) < thr1) ? q1 : 0.f;
                md1  += q1 * (&mi1[t].x)[u] * mav;
            }
        }
        #pragma unroll
        for (int off = 32; off > 0; off >>= 1) {
            ids0 += __shfl_xor(ids0, off, 64);
            ids1 += __shfl_xor(ids1, off, 64);
            md0  += __shfl_xor(md0,  off, 64);
            md1  += __shfl_xor(md1,  off, 64);
        }
        const float mod0 = sqrtf(fmaxf(md0, 1e-12f));
        const float mod1 = sqrtf(fmaxf(md1, 1e-12f));
        max0 = fmaxf(max0, mod0);
        max1 = fmaxf(max1, mod1);
        float id0 = sqrtf(fmaxf(ids0, 1e-12f));
        float id1 = sqrtf(fmaxf(ids1, 1e-12f));
        const int tj = targets[j];
        if (tj != t0) min0 = fminf(min0, id0); else id0 = INFINITY;
        if (tj != t1) min1 = fminf(min1, id1); else id1 = INFINITY;
        if (lane == 0) {                       // j-side (transposed) partials
            pmaxT[j * NP + p] = fmaxf(mod0, mod1);
            pminT[j * NP + p] = fminf(id0, id1);
        }
    }
    if (lane == 0) {                           // i-side partials
        pmax[i0 * NTILE + jt] = max0;
        pmax[i1 * NTILE + jt] = max1;
        pmin[i0 * NTILE + jt] = min0;
        pmin[i1 * NTILE + jt] = min1;
    }
}

// ---------------------------------------------------------------------------
// Kernel C: parallel final reduce. One wave per row: <=3 guarded loads per
// lane, 6-step max/min butterfly, atomicAdd of per_row/BB; last block
// publishes the total to d_out. Valid slots: i-side jt in [i/4, 64),
// transposed p < 2*(i/4)+2 — poisoned slots never read.
// ---------------------------------------------------------------------------
__global__ __launch_bounds__(64) void final_kernel(
    const float* __restrict__ pmax, const float* __restrict__ pmin,
    const float* __restrict__ pmaxT, const float* __restrict__ pminT,
    float* __restrict__ acc, unsigned int* __restrict__ cnt_g,
    float* __restrict__ out)
{
    const int i = blockIdx.x;       // row
    const int lane = threadIdx.x;
    const int s = i >> 2;
    float mx = 0.f, mn = INFINITY;
    const int t = s + lane;
    if (t < NTILE) {
        mx = fmaxf(mx, pmax[i * NTILE + t]);
        mn = fminf(mn, pmin[i * NTILE + t]);
    }
    const int pv = 2 * s + 2;
    if (lane < pv) {
        mx = fmaxf(mx, pmaxT[i * NP + lane]);
        mn = fminf(mn, pminT[i * NP + lane]);
    }
    if (lane + 64 < pv) {
        mx = fmaxf(mx, pmaxT[i * NP + lane + 64]);
        mn = fminf(mn, pminT[i * NP + lane + 64]);
    }
    #pragma unroll
    for (int off = 32; off > 0; off >>= 1) {
        mx = fmaxf(mx, __shfl_xor(mx, off, 64));
        mn = fminf(mn, __shfl_xor(mn, off, 64));
    }
    if (lane == 0) {
        const float per = fmaxf(mx * 10.f - mn, 0.f);
        atomicAdd(acc, per * (1.0f / BB));
        __threadfence();
        const unsigned int old = atomicAdd(cnt_g, 1u);
        if (old == BB - 1) {
            __threadfence();
            out[0] = atomicAdd(acc, 0.0f);   // device-coherent read-back
        }
    }
}

extern "C" void kernel_launch(void* const* d_in, const int* in_sizes, int n_in,
                              void* d_out, int out_size, void* d_ws, size_t ws_size,
                              hipStream_t stream)
{
    const float* x       = (const float*)d_in[0];
    const int*   targets = (const int*)d_in[1];
    const int*   subs    = (const int*)d_in[2];
    const int*   m_count = (const int*)d_in[3];
    float* out  = (float*)d_out;

    float* mcsq  = (float*)d_ws;                  // BB*CC floats = 1 MB
    float* pmax  = mcsq  + (long)BB * CC;         // BB*NTILE
    float* pmin  = pmax  + BB * NTILE;            // BB*NTILE
    float* pmaxT = pmin  + BB * NTILE;            // BB*NP
    float* pminT = pmaxT + BB * NP;               // BB*NP
    float* acc   = pminT + BB * NP;               // 1
    unsigned int* cnt_g = (unsigned int*)(acc + 1);

    mcsq_kernel <<<BB,   64, 0, stream>>>(x, targets, subs, m_count, mcsq, acc, cnt_g);
    pair_kernel <<<1040, 256, 0, stream>>>(x, mcsq, targets, pmax, pmin, pmaxT, pminT);
    final_kernel<<<BB,   64, 0, stream>>>(pmax, pmin, pmaxT, pminT, acc, cnt_g, out);
}